// Round 2
// baseline (19703.606 us; speedup 1.0000x reference)
//
#include <hip/hip_runtime.h>
#include <hip/hip_bf16.h>

#define SEQ    256
#define BATCH  64
#define EMB    256
#define HID    1024
#define GATES  3072   // 3*HID
#define NCLS   128
#define TCH    32                 // time chunk
#define ROWS   (TCH * BATCH)      // 2048 rows per chunk

// ---------------------------------------------------------------------------
// f32 GEMM:  C[M,N] = A[M,K] * Bw[N,K]^T + bias[N], 64x64 tile, 256 thr, 4x4.
// MODE 0: A = dense chunk buffer [ROWS,K], store C row-major [ROWS,N]
// MODE 1: A row g=row_base+r gathered from embed[x[b*SEQ+s]] (s=g>>6,b=g&63)
// MODE 2: A dense, store remapped: C[(b*SEQ+s)*NCLS + col]
// ---------------------------------------------------------------------------
template <int MODE>
__global__ void gemm_bias(const float* __restrict__ A, const float* __restrict__ Bw,
                          const float* __restrict__ bias, float* __restrict__ Cout,
                          int N, int K, const int* __restrict__ xidx,
                          const float* __restrict__ emb, int row_base) {
    __shared__ float As[32][64];
    __shared__ float Bs[32][64];
    const int row0 = blockIdx.x * 64;
    const int col0 = blockIdx.y * 64;
    const int tid = threadIdx.x;
    const int tx = tid & 15, ty = tid >> 4;
    const int lr = tid >> 3;          // 0..31
    const int lk = (tid & 7) * 4;     // 0,4,...,28

    float acc[4][4] = {};

    for (int kk = 0; kk < K; kk += 32) {
#pragma unroll
        for (int p = 0; p < 2; ++p) {
            int m = p * 32 + lr;
            float4 av;
            if (MODE == 1) {
                int g = row_base + row0 + m;
                int s = g >> 6, b = g & 63;
                int idx = xidx[b * SEQ + s];
                av = *(const float4*)&emb[(size_t)idx * K + kk + lk];
            } else {
                av = *(const float4*)&A[(size_t)(row0 + m) * K + kk + lk];
            }
            As[lk + 0][m] = av.x; As[lk + 1][m] = av.y;
            As[lk + 2][m] = av.z; As[lk + 3][m] = av.w;
            float4 bv = *(const float4*)&Bw[(size_t)(col0 + m) * K + kk + lk];
            Bs[lk + 0][m] = bv.x; Bs[lk + 1][m] = bv.y;
            Bs[lk + 2][m] = bv.z; Bs[lk + 3][m] = bv.w;
        }
        __syncthreads();
#pragma unroll
        for (int k = 0; k < 32; ++k) {
            float4 a = *(const float4*)&As[k][ty * 4];
            float4 b = *(const float4*)&Bs[k][tx * 4];
            acc[0][0] += a.x * b.x; acc[0][1] += a.x * b.y; acc[0][2] += a.x * b.z; acc[0][3] += a.x * b.w;
            acc[1][0] += a.y * b.x; acc[1][1] += a.y * b.y; acc[1][2] += a.y * b.z; acc[1][3] += a.y * b.w;
            acc[2][0] += a.z * b.x; acc[2][1] += a.z * b.y; acc[2][2] += a.z * b.z; acc[2][3] += a.z * b.w;
            acc[3][0] += a.w * b.x; acc[3][1] += a.w * b.y; acc[3][2] += a.w * b.z; acc[3][3] += a.w * b.w;
        }
        __syncthreads();
    }

#pragma unroll
    for (int i = 0; i < 4; ++i) {
#pragma unroll
        for (int j = 0; j < 4; ++j) {
            int row = row0 + ty * 4 + i;
            int col = col0 + tx * 4 + j;
            float v = acc[i][j] + bias[col];
            if (MODE == 2) {
                int g = row_base + row;
                int s = g >> 6, b = g & 63;
                Cout[((size_t)(b * SEQ + s)) * NCLS + col] = v;
            } else {
                Cout[(size_t)row * N + col] = v;
            }
        }
    }
}

// ---------------------------------------------------------------------------
// One GRU time step (t is chunk-local). 256 blocks x 256 threads.
// ---------------------------------------------------------------------------
__global__ void gru_step(const float* __restrict__ gi, const float* __restrict__ w_hh,
                         const float* __restrict__ b_hh, const float* __restrict__ h_in,
                         float* __restrict__ h_out, float* __restrict__ outseq, int t) {
    const int bg = blockIdx.x >> 6;
    const int cc = blockIdx.x & 63;
    const int b0 = bg * 16, j0 = cc * 16;
    const int tid = threadIdx.x;
    const int tj = tid & 15, tb = tid >> 4;

    __shared__ float Hs[16][68];
    __shared__ float Ws[48][68];

    const int lrow = tid >> 4;        // 0..15
    const int lk = (tid & 15) * 4;    // 0..60

    float accr = 0.f, accz = 0.f, accn = 0.f;

    for (int kk = 0; kk < HID; kk += 64) {
        *(float4*)&Hs[lrow][lk] = *(const float4*)&h_in[(size_t)(b0 + lrow) * HID + kk + lk];
#pragma unroll
        for (int g = 0; g < 3; ++g) {
            *(float4*)&Ws[g * 16 + lrow][lk] =
                *(const float4*)&w_hh[(size_t)(g * HID + j0 + lrow) * HID + kk + lk];
        }
        __syncthreads();
#pragma unroll
        for (int k = 0; k < 64; k += 4) {
            float4 hv = *(const float4*)&Hs[tb][k];
            float4 wr = *(const float4*)&Ws[tj][k];
            float4 wz = *(const float4*)&Ws[16 + tj][k];
            float4 wn = *(const float4*)&Ws[32 + tj][k];
            accr += hv.x * wr.x + hv.y * wr.y + hv.z * wr.z + hv.w * wr.w;
            accz += hv.x * wz.x + hv.y * wz.y + hv.z * wz.z + hv.w * wz.w;
            accn += hv.x * wn.x + hv.y * wn.y + hv.z * wn.z + hv.w * wn.w;
        }
        __syncthreads();
    }

    const int b = b0 + tb, j = j0 + tj;
    accr += b_hh[j];
    accz += b_hh[HID + j];
    accn += b_hh[2 * HID + j];

    const float* git = &gi[((size_t)(t * BATCH + b)) * GATES];
    float r = 1.f / (1.f + __expf(-(git[j] + accr)));
    float z = 1.f / (1.f + __expf(-(git[HID + j] + accz)));
    float n = tanhf(git[2 * HID + j] + r * accn);
    float hprev = h_in[(size_t)b * HID + j];
    float hn = (1.f - z) * n + z * hprev;

    h_out[(size_t)b * HID + j] = hn;
    outseq[((size_t)(t * BATCH + b)) * HID + j] = hn;
}

// ---------------------------------------------------------------------------
extern "C" void kernel_launch(void* const* d_in, const int* in_sizes, int n_in,
                              void* d_out, int out_size, void* d_ws, size_t ws_size,
                              hipStream_t stream) {
    const int*   x      = (const int*)d_in[0];
    const float* hs     = (const float*)d_in[1];
    const float* emb    = (const float*)d_in[2];
    const float* w_ih0  = (const float*)d_in[3];
    const float* w_hh0  = (const float*)d_in[4];
    const float* b_ih0  = (const float*)d_in[5];
    const float* b_hh0  = (const float*)d_in[6];
    const float* w_ih1  = (const float*)d_in[7];
    const float* w_hh1  = (const float*)d_in[8];
    const float* b_ih1  = (const float*)d_in[9];
    const float* b_hh1  = (const float*)d_in[10];
    const float* w_proj = (const float*)d_in[11];
    const float* b_proj = (const float*)d_in[12];

    float* logits = (float*)d_out;                       // [B*S, 128]
    float* hT     = logits + (size_t)SEQ * BATCH * NCLS; // [2, 64, 1024]

    // workspace: ~43 MB total
    float* ws    = (float*)d_ws;
    float* gi    = ws;                          // ROWS*GATES = 6291456
    float* h0seq = gi + (size_t)ROWS * GATES;   // ROWS*HID   = 2097152
    float* h1seq = h0seq + (size_t)ROWS * HID;  // ROWS*HID   = 2097152
    float* h0a   = h1seq + (size_t)ROWS * HID;  // 65536
    float* h0b   = h0a + 65536;
    float* h1a   = h0b + 65536;
    float* h1b   = h1a + 65536;

    hipMemcpyAsync(h0a, hs, 65536 * sizeof(float), hipMemcpyDeviceToDevice, stream);
    hipMemcpyAsync(h1a, hs + 65536, 65536 * sizeof(float), hipMemcpyDeviceToDevice, stream);

    float* h0[2] = {h0a, h0b};
    float* h1[2] = {h1a, h1b};
    int p0 = 0, p1 = 0;

    dim3 gg(ROWS / 64, GATES / 64);   // (32, 48)
    dim3 gp(ROWS / 64, NCLS / 64);    // (32, 2)

    for (int c = 0; c < SEQ / TCH; ++c) {
        int row_base = c * ROWS;

        // gi = embed[x] @ w_ih0^T + b_ih0  (gather-fused)
        gemm_bias<1><<<gg, 256, 0, stream>>>(nullptr, w_ih0, b_ih0, gi, GATES, EMB, x, emb, row_base);

        for (int t = 0; t < TCH; ++t) {
            gru_step<<<256, 256, 0, stream>>>(gi, w_hh0, b_hh0, h0[p0], h0[p0 ^ 1], h0seq, t);
            p0 ^= 1;
        }

        // gi = h0seq @ w_ih1^T + b_ih1   (reuse gi buffer)
        gemm_bias<0><<<gg, 256, 0, stream>>>(h0seq, w_ih1, b_ih1, gi, GATES, HID, nullptr, nullptr, 0);

        for (int t = 0; t < TCH; ++t) {
            gru_step<<<256, 256, 0, stream>>>(gi, w_hh1, b_hh1, h1[p1], h1[p1 ^ 1], h1seq, t);
            p1 ^= 1;
        }

        // logits chunk = h1seq @ w_proj^T + b_proj  (remapped store)
        gemm_bias<2><<<gp, 256, 0, stream>>>(h1seq, w_proj, b_proj, logits, NCLS, HID, nullptr, nullptr, row_base);
    }

    hipMemcpyAsync(hT, h0[p0], 65536 * sizeof(float), hipMemcpyDeviceToDevice, stream);
    hipMemcpyAsync(hT + 65536, h1[p1], 65536 * sizeof(float), hipMemcpyDeviceToDevice, stream);
}

// Round 3
// 5669.519 us; speedup vs baseline: 3.4754x; 3.4754x over previous
//
#include <hip/hip_runtime.h>
#include <hip/hip_bf16.h>

#define SEQ    256
#define BATCH  64
#define EMB    256
#define HID    1024
#define GATES  3072   // 3*HID
#define NCLS   128
#define TCH    16                 // time chunk
#define ROWS   (TCH * BATCH)      // 1024 rows per chunk

typedef __attribute__((ext_vector_type(8))) short bf16x8;
typedef __attribute__((ext_vector_type(4))) float f32x4;

__device__ inline unsigned short f2bf(float x) {
    union { float f; unsigned int u; } v; v.f = x;
    v.u += 0x7fffu + ((v.u >> 16) & 1u);   // RNE
    return (unsigned short)(v.u >> 16);
}

// ---------------------------------------------------------------------------
// f32 -> bf16 conversion (n divisible by 4)
// ---------------------------------------------------------------------------
__global__ void conv_bf16(const float* __restrict__ in, unsigned short* __restrict__ out, int n) {
    int i = (blockIdx.x * 256 + threadIdx.x) * 4;
    if (i < n) {
        float4 v = *(const float4*)(in + i);
        out[i + 0] = f2bf(v.x); out[i + 1] = f2bf(v.y);
        out[i + 2] = f2bf(v.z); out[i + 3] = f2bf(v.w);
    }
}

// ---------------------------------------------------------------------------
// bf16 MFMA GEMM: C[M,N] = A[M,K] * Bw[N,K]^T + bias[N]
// block = 256 thr (4 waves), tile 64Mx64N; wave w owns m-subtile, 4 n-frags.
// MODE 0: A dense bf16, store f32 row-major [row][N]
// MODE 1: A rows gathered from emb_bf16 via x (row g=row_base+r, s=g>>6,b=g&63)
// MODE 2: A dense bf16, store f32 remapped C[(b*SEQ+s)*NCLS + col]
// ---------------------------------------------------------------------------
template <int MODE>
__global__ void gemm_mfma(const unsigned short* __restrict__ A,
                          const unsigned short* __restrict__ Bw,
                          const float* __restrict__ bias, float* __restrict__ Cout,
                          int N, int K, const int* __restrict__ xidx,
                          const unsigned short* __restrict__ emb, int row_base) {
    const int tid = threadIdx.x;
    const int w = tid >> 6, l = tid & 63;
    const int m0 = blockIdx.x * 64 + w * 16;
    const int n0 = blockIdx.y * 64;
    const int la = l & 15, lk = (l >> 4) * 8;

    const unsigned short* arow;
    if (MODE == 1) {
        int g = row_base + m0 + la;
        int s = g >> 6, b = g & 63;
        arow = emb + (size_t)xidx[b * SEQ + s] * K + lk;
    } else {
        arow = A + (size_t)(m0 + la) * K + lk;
    }
    const unsigned short* brow = Bw + (size_t)(n0 + la) * K + lk;

    f32x4 acc[4] = {};
    for (int k = 0; k < K; k += 32) {
        bf16x8 a = *(const bf16x8*)(arow + k);
#pragma unroll
        for (int nt = 0; nt < 4; ++nt) {
            bf16x8 bb = *(const bf16x8*)(brow + (size_t)nt * 16 * K + k);
            acc[nt] = __builtin_amdgcn_mfma_f32_16x16x32_bf16(a, bb, acc[nt], 0, 0, 0);
        }
    }

    const int rbase = (l >> 4) * 4;
#pragma unroll
    for (int nt = 0; nt < 4; ++nt) {
        int colg = n0 + nt * 16 + la;
        float bsv = bias[colg];
#pragma unroll
        for (int i = 0; i < 4; ++i) {
            int rowg = m0 + rbase + i;
            float v = acc[nt][i] + bsv;
            if (MODE == 2) {
                int g = row_base + rowg;
                int s = g >> 6, b = g & 63;
                Cout[((size_t)(b * SEQ + s)) * NCLS + colg] = v;
            } else {
                Cout[(size_t)rowg * N + colg] = v;
            }
        }
    }
}

// ---------------------------------------------------------------------------
// One GRU step, MFMA. 256 blocks (4 batch-groups x 64 j-tiles) x 256 thr.
// Waves 0..2 compute gate r/z/n 16x16 tile over K=1024; wave 3 idles in GEMM.
// Gate tiles exchanged via LDS; pointwise update fused.
// Recurrent state: f32 (hprev_f) for the update; bf16 (hprev_b) feeds MFMA.
// ---------------------------------------------------------------------------
__global__ void gru_step_mfma(const float* __restrict__ gi,
                              const unsigned short* __restrict__ whb,  // [3072][1024] bf16
                              const float* __restrict__ b_hh,
                              const float* __restrict__ hprev_f,
                              const unsigned short* __restrict__ hprev_b,
                              float* __restrict__ hout_f,
                              unsigned short* __restrict__ hout_b,
                              unsigned short* __restrict__ outseq_b,   // [ROWS][1024] bf16
                              int tloc) {
    const int bg = blockIdx.x >> 6;
    const int jt = blockIdx.x & 63;
    const int b0 = bg * 16, j0 = jt * 16;
    const int tid = threadIdx.x;
    const int g = tid >> 6;      // wave = gate (3 = idle)
    const int l = tid & 63;

    __shared__ float sg[3][256];

    if (g < 3) {
        f32x4 acc = {};
        const unsigned short* hrow = hprev_b + (size_t)(b0 + (l & 15)) * HID + ((l >> 4) * 8);
        const unsigned short* wrow = whb + (size_t)(g * HID + j0 + (l & 15)) * HID + ((l >> 4) * 8);
#pragma unroll
        for (int ks = 0; ks < 32; ++ks) {
            bf16x8 a = *(const bf16x8*)(hrow + ks * 32);
            bf16x8 b = *(const bf16x8*)(wrow + ks * 32);
            acc = __builtin_amdgcn_mfma_f32_16x16x32_bf16(a, b, acc, 0, 0, 0);
        }
        const int col = l & 15, rbase = (l >> 4) * 4;
#pragma unroll
        for (int i = 0; i < 4; ++i) sg[g][(rbase + i) * 16 + col] = acc[i];
    }
    __syncthreads();

    const int row = tid >> 4, col = tid & 15;
    const int b = b0 + row, j = j0 + col;
    const float ghr = sg[0][tid] + b_hh[j];
    const float ghz = sg[1][tid] + b_hh[HID + j];
    const float ghn = sg[2][tid] + b_hh[2 * HID + j];
    const float* git = gi + ((size_t)(tloc * BATCH + b)) * GATES;
    float r = 1.f / (1.f + __expf(-(git[j] + ghr)));
    float z = 1.f / (1.f + __expf(-(git[HID + j] + ghz)));
    float n = tanhf(git[2 * HID + j] + r * ghn);
    float hp = hprev_f[(size_t)b * HID + j];
    float hn = (1.f - z) * n + z * hp;

    hout_f[(size_t)b * HID + j] = hn;
    unsigned short hb = f2bf(hn);
    hout_b[(size_t)b * HID + j] = hb;
    outseq_b[((size_t)(tloc * BATCH + b)) * HID + j] = hb;
}

// ---------------------------------------------------------------------------
extern "C" void kernel_launch(void* const* d_in, const int* in_sizes, int n_in,
                              void* d_out, int out_size, void* d_ws, size_t ws_size,
                              hipStream_t stream) {
    const int*   x      = (const int*)d_in[0];
    const float* hs     = (const float*)d_in[1];
    const float* emb    = (const float*)d_in[2];
    const float* w_ih0  = (const float*)d_in[3];
    const float* w_hh0  = (const float*)d_in[4];
    const float* b_ih0  = (const float*)d_in[5];
    const float* b_hh0  = (const float*)d_in[6];
    const float* w_ih1  = (const float*)d_in[7];
    const float* w_hh1  = (const float*)d_in[8];
    const float* b_ih1  = (const float*)d_in[9];
    const float* b_hh1  = (const float*)d_in[10];
    const float* w_proj = (const float*)d_in[11];
    const float* b_proj = (const float*)d_in[12];

    float* logits = (float*)d_out;                       // [B*S, 128] f32
    float* hT     = logits + (size_t)SEQ * BATCH * NCLS; // [2, 64, 1024] f32

    // ---- workspace layout (bytes) ----
    char* p = (char*)d_ws;
    float* gi = (float*)p;                 p += (size_t)ROWS * GATES * 4;   // 12.6 MB
    float* h0f[2]; h0f[0] = (float*)p;     p += 65536 * 4;
    h0f[1] = (float*)p;                    p += 65536 * 4;
    float* h1f[2]; h1f[0] = (float*)p;     p += 65536 * 4;
    h1f[1] = (float*)p;                    p += 65536 * 4;
    unsigned short* h0b[2]; h0b[0] = (unsigned short*)p; p += 65536 * 2;
    h0b[1] = (unsigned short*)p;           p += 65536 * 2;
    unsigned short* h1b[2]; h1b[0] = (unsigned short*)p; p += 65536 * 2;
    h1b[1] = (unsigned short*)p;           p += 65536 * 2;
    unsigned short* out0b = (unsigned short*)p; p += (size_t)ROWS * HID * 2;  // 2.1 MB
    unsigned short* out1b = (unsigned short*)p; p += (size_t)ROWS * HID * 2;  // 2.1 MB
    unsigned short* embB  = (unsigned short*)p; p += (size_t)NCLS * EMB * 2;
    unsigned short* wih0B = (unsigned short*)p; p += (size_t)GATES * EMB * 2;
    unsigned short* whh0B = (unsigned short*)p; p += (size_t)GATES * HID * 2;
    unsigned short* wih1B = (unsigned short*)p; p += (size_t)GATES * HID * 2;
    unsigned short* whh1B = (unsigned short*)p; p += (size_t)GATES * HID * 2;
    unsigned short* wprojB = (unsigned short*)p; p += (size_t)NCLS * HID * 2;

    // ---- one-time weight conversions ----
    conv_bf16<<<(NCLS * EMB) / 1024, 256, 0, stream>>>(emb, embB, NCLS * EMB);
    conv_bf16<<<(GATES * EMB) / 1024, 256, 0, stream>>>(w_ih0, wih0B, GATES * EMB);
    conv_bf16<<<(GATES * HID) / 1024, 256, 0, stream>>>(w_hh0, whh0B, GATES * HID);
    conv_bf16<<<(GATES * HID) / 1024, 256, 0, stream>>>(w_ih1, wih1B, GATES * HID);
    conv_bf16<<<(GATES * HID) / 1024, 256, 0, stream>>>(w_hh1, whh1B, GATES * HID);
    conv_bf16<<<(NCLS * HID) / 1024, 256, 0, stream>>>(w_proj, wprojB, NCLS * HID);

    // ---- init hidden state ----
    hipMemcpyAsync(h0f[0], hs, 65536 * 4, hipMemcpyDeviceToDevice, stream);
    hipMemcpyAsync(h1f[0], hs + 65536, 65536 * 4, hipMemcpyDeviceToDevice, stream);
    conv_bf16<<<64, 256, 0, stream>>>(hs, h0b[0], 65536);
    conv_bf16<<<64, 256, 0, stream>>>(hs + 65536, h1b[0], 65536);

    int p0 = 0, p1 = 0;
    dim3 gg(ROWS / 64, GATES / 64);   // (16, 48)
    dim3 gp(ROWS / 64, NCLS / 64);    // (16, 2)

    for (int c = 0; c < SEQ / TCH; ++c) {
        int row_base = c * ROWS;

        // gi = embed[x] @ w_ih0^T + b_ih0 (gathered A)
        gemm_mfma<1><<<gg, 256, 0, stream>>>(nullptr, wih0B, b_ih0, gi, GATES, EMB, x, embB, row_base);

        for (int t = 0; t < TCH; ++t) {
            gru_step_mfma<<<256, 256, 0, stream>>>(gi, whh0B, b_hh0,
                h0f[p0], h0b[p0], h0f[p0 ^ 1], h0b[p0 ^ 1], out0b, t);
            p0 ^= 1;
        }

        // gi = out0 @ w_ih1^T + b_ih1
        gemm_mfma<0><<<gg, 256, 0, stream>>>(out0b, wih1B, b_ih1, gi, GATES, HID, nullptr, nullptr, 0);

        for (int t = 0; t < TCH; ++t) {
            gru_step_mfma<<<256, 256, 0, stream>>>(gi, whh1B, b_hh1,
                h1f[p1], h1b[p1], h1f[p1 ^ 1], h1b[p1 ^ 1], out1b, t);
            p1 ^= 1;
        }

        // logits chunk = out1 @ w_proj^T + b_proj (remapped store)
        gemm_mfma<2><<<gp, 256, 0, stream>>>(out1b, wprojB, b_proj, logits, NCLS, HID, nullptr, nullptr, row_base);
    }

    hipMemcpyAsync(hT, h0f[p0], 65536 * 4, hipMemcpyDeviceToDevice, stream);
    hipMemcpyAsync(hT + 65536, h1f[p1], 65536 * 4, hipMemcpyDeviceToDevice, stream);
}